// Round 5
// baseline (250.996 us; speedup 1.0000x reference)
//
#include <hip/hip_runtime.h>
#include <math.h>

#define BDIM 8
#define IMG 224
#define PP 16
#define GG 14
#define NN 196
#define PD 256
#define DD 128
#define DFFV 256
#define CC 1000

#define NEGINF (-INFINITY)

// monotonic float<->uint order-preserving encoding for atomicMax pooling
__device__ __forceinline__ unsigned keyenc(float f) {
  unsigned u = __float_as_uint(f);
  return (u & 0x80000000u) ? ~u : (u | 0x80000000u);
}
__device__ __forceinline__ float keydec(unsigned k) {
  unsigned u = (k & 0x80000000u) ? (k & 0x7fffffffu) : ~k;
  return __uint_as_float(u);
}

// ============ K1: embed + qkv(L0). grid (98, B), 128 threads =============
// Block owns rows n0, n0+1. 3 outputs (q,k,v) per thread in qkv phase.
__global__ __launch_bounds__(128) void embed_qkv_kernel(
    const float* __restrict__ x, const float* __restrict__ eW,
    const float* __restrict__ pos, const float* __restrict__ qW,
    const float* __restrict__ kW, const float* __restrict__ vW,
    float* __restrict__ h, float* __restrict__ qg, float* __restrict__ kg,
    float* __restrict__ vg, unsigned* __restrict__ poolkey) {
  int nt = blockIdx.x, b = blockIdx.y, n0 = nt * 2;
  __shared__ float patch[2][PD];  // 2 KB
  __shared__ float hrow[2][DD];   // 1 KB
  __shared__ float red[2][2];
  int t = threadIdx.x;
  if (nt == 0) poolkey[b * DD + t] = 0u;  // init pool keys for this batch
  // stage 2 patches: 128 float4s, one per thread
  {
    int p = t >> 6, r = t & 63, pi = r >> 2, pj4 = r & 3;
    int n = n0 + p, gi = n / GG, gj = n % GG;
    float4 v = *reinterpret_cast<const float4*>(
        x + (size_t)(b * IMG + gi * PP + pi) * IMG + gj * PP + pj4 * 4);
    *reinterpret_cast<float4*>(&patch[p][pi * PP + pj4 * 4]) = v;
  }
  __syncthreads();
  // embed: thread t = dim d, both rows
  float a0 = NEGINF, a1 = NEGINF;
  {
    const float4* W4 = reinterpret_cast<const float4*>(eW + (size_t)t * PD);
#pragma unroll 4
    for (int j4 = 0; j4 < PD / 4; j4++) {
      float4 w = W4[j4];
      float4 p0 = *reinterpret_cast<const float4*>(&patch[0][j4 * 4]);
      float4 p1 = *reinterpret_cast<const float4*>(&patch[1][j4 * 4]);
      a0 = fmaxf(a0, p0.x + w.x); a0 = fmaxf(a0, p0.y + w.y);
      a0 = fmaxf(a0, p0.z + w.z); a0 = fmaxf(a0, p0.w + w.w);
      a1 = fmaxf(a1, p1.x + w.x); a1 = fmaxf(a1, p1.y + w.y);
      a1 = fmaxf(a1, p1.z + w.z); a1 = fmaxf(a1, p1.w + w.w);
    }
  }
  float h0 = a0 + pos[(size_t)n0 * DD + t];
  float h1v = a1 + pos[(size_t)(n0 + 1) * DD + t];
  hrow[0][t] = h0; hrow[1][t] = h1v;
  h[(size_t)(b * NN + n0) * DD + t] = h0;
  h[(size_t)(b * NN + n0 + 1) * DD + t] = h1v;
  // rowmax (pnorm constants) from registers
  {
    float m0 = h0, m1 = h1v;
#pragma unroll
    for (int mask = 32; mask >= 1; mask >>= 1) {
      m0 = fmaxf(m0, __shfl_xor(m0, mask));
      m1 = fmaxf(m1, __shfl_xor(m1, mask));
    }
    if ((t & 63) == 0) { red[t >> 6][0] = m0; red[t >> 6][1] = m1; }
  }
  __syncthreads();
  float mx0 = fmaxf(red[0][0], red[1][0]);
  float mx1 = fmaxf(red[0][1], red[1][1]);
  // qkv: thread t = dim i of q AND k AND v (3 outputs x 2 rows)
  float aq0 = NEGINF, aq1 = NEGINF, ak0 = NEGINF, ak1 = NEGINF,
        av0 = NEGINF, av1 = NEGINF;
  {
    const float4* Q4 = reinterpret_cast<const float4*>(qW + (size_t)t * DD);
    const float4* K4 = reinterpret_cast<const float4*>(kW + (size_t)t * DD);
    const float4* V4 = reinterpret_cast<const float4*>(vW + (size_t)t * DD);
#pragma unroll 4
    for (int j4 = 0; j4 < DD / 4; j4++) {
      float4 x0 = *reinterpret_cast<const float4*>(&hrow[0][j4 * 4]);
      float4 x1 = *reinterpret_cast<const float4*>(&hrow[1][j4 * 4]);
      float4 wq = Q4[j4], wk = K4[j4], wv = V4[j4];
      aq0 = fmaxf(aq0, x0.x + wq.x); aq0 = fmaxf(aq0, x0.y + wq.y);
      aq0 = fmaxf(aq0, x0.z + wq.z); aq0 = fmaxf(aq0, x0.w + wq.w);
      aq1 = fmaxf(aq1, x1.x + wq.x); aq1 = fmaxf(aq1, x1.y + wq.y);
      aq1 = fmaxf(aq1, x1.z + wq.z); aq1 = fmaxf(aq1, x1.w + wq.w);
      ak0 = fmaxf(ak0, x0.x + wk.x); ak0 = fmaxf(ak0, x0.y + wk.y);
      ak0 = fmaxf(ak0, x0.z + wk.z); ak0 = fmaxf(ak0, x0.w + wk.w);
      ak1 = fmaxf(ak1, x1.x + wk.x); ak1 = fmaxf(ak1, x1.y + wk.y);
      ak1 = fmaxf(ak1, x1.z + wk.z); ak1 = fmaxf(ak1, x1.w + wk.w);
      av0 = fmaxf(av0, x0.x + wv.x); av0 = fmaxf(av0, x0.y + wv.y);
      av0 = fmaxf(av0, x0.z + wv.z); av0 = fmaxf(av0, x0.w + wv.w);
      av1 = fmaxf(av1, x1.x + wv.x); av1 = fmaxf(av1, x1.y + wv.y);
      av1 = fmaxf(av1, x1.z + wv.z); av1 = fmaxf(av1, x1.w + wv.w);
    }
  }
  size_t b0 = (size_t)(b * NN + n0) * DD + t, b1 = b0 + DD;
  qg[b0] = aq0 - mx0; qg[b1] = aq1 - mx1;
  kg[b0] = ak0 - mx0; kg[b1] = ak1 - mx1;
  vg[b0] = av0 - mx0; vg[b1] = av1 - mx1;
}

// ===== K2/K3: attn + ffn1 + ffn2 (+ next qkv | pool). grid (98,B), 128 thr =
__global__ __launch_bounds__(128) void layer_kernel(
    const float* __restrict__ qg, const float* __restrict__ kg,
    const float* __restrict__ vg, float* __restrict__ h,
    const float* __restrict__ f1W, const float* __restrict__ f2W,
    const float* __restrict__ tau, const float* __restrict__ qWn,
    const float* __restrict__ kWn, const float* __restrict__ vWn,
    float* __restrict__ qo, float* __restrict__ ko, float* __restrict__ vo,
    unsigned* __restrict__ poolkey) {
  int nt = blockIdx.x, b = blockIdx.y, i0 = nt * 2;
  __shared__ float qs[2][DD];       // 1 KB
  __shared__ float hrow[2][DD];     // 1 KB
  __shared__ float2 sc[NN];         // 1.6 KB  sc[j] = {score_row0, score_row1}
  __shared__ float h1s[2][DFFV];    // 2 KB
  __shared__ float part[4][2][DD];  // 4 KB  PV partials
  __shared__ float redA[2][2];
  __shared__ float redB[2][2];
  int t = threadIdx.x;
  int wv = t >> 6, lane0 = (t & 63) == 0;
  // ---- stage own q rows and h rows ----
  if (t < 64) {
    float4 val = reinterpret_cast<const float4*>(qg + (size_t)(b * NN + i0) * DD)[t];
    *reinterpret_cast<float4*>(&qs[0][0] + t * 4) = val;
  } else {
    int tt = t - 64;
    float4 val = reinterpret_cast<const float4*>(h + (size_t)(b * NN + i0) * DD)[tt];
    *reinterpret_cast<float4*>(&hrow[0][0] + tt * 4) = val;
  }
  __syncthreads();
  // ---- scores: thread t handles keys t and (t+128 if valid), both q rows --
  {
    int j2 = (t < NN - DD) ? (t + DD) : t;  // clamped (safe) second key
    const float4* ka4 = reinterpret_cast<const float4*>(kg + (size_t)(b * NN + t) * DD);
    const float4* kb4 = reinterpret_cast<const float4*>(kg + (size_t)(b * NN + j2) * DD);
    float sa0 = NEGINF, sa1 = NEGINF, sb0 = NEGINF, sb1 = NEGINF;
#pragma unroll 4
    for (int d4 = 0; d4 < DD / 4; d4++) {
      float4 q0 = *reinterpret_cast<const float4*>(&qs[0][d4 * 4]);
      float4 q1 = *reinterpret_cast<const float4*>(&qs[1][d4 * 4]);
      float4 ja = ka4[d4], jb = kb4[d4];
      sa0 = fmaxf(sa0, q0.x + ja.x); sa0 = fmaxf(sa0, q0.y + ja.y);
      sa0 = fmaxf(sa0, q0.z + ja.z); sa0 = fmaxf(sa0, q0.w + ja.w);
      sa1 = fmaxf(sa1, q1.x + ja.x); sa1 = fmaxf(sa1, q1.y + ja.y);
      sa1 = fmaxf(sa1, q1.z + ja.z); sa1 = fmaxf(sa1, q1.w + ja.w);
      sb0 = fmaxf(sb0, q0.x + jb.x); sb0 = fmaxf(sb0, q0.y + jb.y);
      sb0 = fmaxf(sb0, q0.z + jb.z); sb0 = fmaxf(sb0, q0.w + jb.w);
      sb1 = fmaxf(sb1, q1.x + jb.x); sb1 = fmaxf(sb1, q1.y + jb.y);
      sb1 = fmaxf(sb1, q1.z + jb.z); sb1 = fmaxf(sb1, q1.w + jb.w);
    }
    sc[t] = make_float2(sa0, sa1);
    if (t < NN - DD) sc[t + DD] = make_float2(sb0, sb1);
  }
  __syncthreads();
  // ---- PV: (d4 = t&31, jg = t>>5 in 0..3), stride-4 over keys ----
  {
    int d4 = t & 31, jg = t >> 5;
    float4 o0 = {NEGINF, NEGINF, NEGINF, NEGINF};
    float4 o1 = o0;
#pragma unroll 4
    for (int j = jg; j < NN; j += 4) {
      float4 vv = *reinterpret_cast<const float4*>(vg + (size_t)(b * NN + j) * DD + d4 * 4);
      float2 c = sc[j];
      o0.x = fmaxf(o0.x, c.x + vv.x); o0.y = fmaxf(o0.y, c.x + vv.y);
      o0.z = fmaxf(o0.z, c.x + vv.z); o0.w = fmaxf(o0.w, c.x + vv.w);
      o1.x = fmaxf(o1.x, c.y + vv.x); o1.y = fmaxf(o1.y, c.y + vv.y);
      o1.z = fmaxf(o1.z, c.y + vv.z); o1.w = fmaxf(o1.w, c.y + vv.w);
    }
    *reinterpret_cast<float4*>(&part[jg][0][d4 * 4]) = o0;
    *reinterpret_cast<float4*>(&part[jg][1][d4 * 4]) = o1;
  }
  __syncthreads();
  // ---- combine PV partials (thread t = dim d), reduce for pnorm ----
  float oacc0, oacc1;
  {
    oacc0 = fmaxf(fmaxf(part[0][0][t], part[1][0][t]), fmaxf(part[2][0][t], part[3][0][t]));
    oacc1 = fmaxf(fmaxf(part[0][1][t], part[1][1][t]), fmaxf(part[2][1][t], part[3][1][t]));
    float m0 = oacc0, m1 = oacc1;
#pragma unroll
    for (int mask = 32; mask >= 1; mask >>= 1) {
      m0 = fmaxf(m0, __shfl_xor(m0, mask));
      m1 = fmaxf(m1, __shfl_xor(m1, mask));
    }
    if (lane0) { redA[wv][0] = m0; redA[wv][1] = m1; }
  }
  __syncthreads();
  // ---- attention pnorm + tropical residual; rowmax of new x -> redB ----
  {
    float om0 = fmaxf(redA[0][0], redA[1][0]);
    float om1 = fmaxf(redA[0][1], redA[1][1]);
    float nh0 = fmaxf(hrow[0][t], oacc0 - om0);
    float nh1 = fmaxf(hrow[1][t], oacc1 - om1);
    hrow[0][t] = nh0; hrow[1][t] = nh1;
    float m0 = nh0, m1 = nh1;
#pragma unroll
    for (int mask = 32; mask >= 1; mask >>= 1) {
      m0 = fmaxf(m0, __shfl_xor(m0, mask));
      m1 = fmaxf(m1, __shfl_xor(m1, mask));
    }
    if (lane0) { redB[wv][0] = m0; redB[wv][1] = m1; }
  }
  __syncthreads();
  // ---- ffn1: thread t -> outputs t and t+128, both rows ----
  {
    float mx0 = fmaxf(redB[0][0], redB[1][0]);
    float mx1 = fmaxf(redB[0][1], redB[1][1]);
    float tv = tau[0];
    const float4* Wa = reinterpret_cast<const float4*>(f1W + (size_t)t * DD);
    const float4* Wb = reinterpret_cast<const float4*>(f1W + (size_t)(t + DD) * DD);
    float a0 = NEGINF, a1 = NEGINF, b0_ = NEGINF, b1_ = NEGINF;
#pragma unroll 4
    for (int j4 = 0; j4 < DD / 4; j4++) {
      float4 x0 = *reinterpret_cast<const float4*>(&hrow[0][j4 * 4]);
      float4 x1 = *reinterpret_cast<const float4*>(&hrow[1][j4 * 4]);
      float4 wa = Wa[j4], wb = Wb[j4];
      a0 = fmaxf(a0, x0.x + wa.x); a0 = fmaxf(a0, x0.y + wa.y);
      a0 = fmaxf(a0, x0.z + wa.z); a0 = fmaxf(a0, x0.w + wa.w);
      a1 = fmaxf(a1, x1.x + wa.x); a1 = fmaxf(a1, x1.y + wa.y);
      a1 = fmaxf(a1, x1.z + wa.z); a1 = fmaxf(a1, x1.w + wa.w);
      b0_ = fmaxf(b0_, x0.x + wb.x); b0_ = fmaxf(b0_, x0.y + wb.y);
      b0_ = fmaxf(b0_, x0.z + wb.z); b0_ = fmaxf(b0_, x0.w + wb.w);
      b1_ = fmaxf(b1_, x1.x + wb.x); b1_ = fmaxf(b1_, x1.y + wb.y);
      b1_ = fmaxf(b1_, x1.z + wb.z); b1_ = fmaxf(b1_, x1.w + wb.w);
    }
    h1s[0][t] = fmaxf(a0 - mx0, tv); h1s[1][t] = fmaxf(a1 - mx1, tv);
    h1s[0][t + DD] = fmaxf(b0_ - mx0, tv); h1s[1][t + DD] = fmaxf(b1_ - mx1, tv);
  }
  __syncthreads();
  // ---- ffn2: thread t = output dim, full 256-j reduce; pnorm reduce -> redA
  float f0 = NEGINF, f1 = NEGINF;
  {
    const float4* W4 = reinterpret_cast<const float4*>(f2W + (size_t)t * DFFV);
#pragma unroll 4
    for (int j4 = 0; j4 < DFFV / 4; j4++) {
      float4 w = W4[j4];
      float4 y0 = *reinterpret_cast<const float4*>(&h1s[0][j4 * 4]);
      float4 y1 = *reinterpret_cast<const float4*>(&h1s[1][j4 * 4]);
      f0 = fmaxf(f0, y0.x + w.x); f0 = fmaxf(f0, y0.y + w.y);
      f0 = fmaxf(f0, y0.z + w.z); f0 = fmaxf(f0, y0.w + w.w);
      f1 = fmaxf(f1, y1.x + w.x); f1 = fmaxf(f1, y1.y + w.y);
      f1 = fmaxf(f1, y1.z + w.z); f1 = fmaxf(f1, y1.w + w.w);
    }
    float m0 = f0, m1 = f1;
#pragma unroll
    for (int mask = 32; mask >= 1; mask >>= 1) {
      m0 = fmaxf(m0, __shfl_xor(m0, mask));
      m1 = fmaxf(m1, __shfl_xor(m1, mask));
    }
    if (lane0) { redA[wv][0] = m0; redA[wv][1] = m1; }
  }
  __syncthreads();
  // ---- ffn pnorm + residual; hand-off ----
  float nh0, nh1;
  {
    float om0 = fmaxf(redA[0][0], redA[1][0]);
    float om1 = fmaxf(redA[0][1], redA[1][1]);
    nh0 = fmaxf(hrow[0][t], f0 - om0);
    nh1 = fmaxf(hrow[1][t], f1 - om1);
    if (qWn == nullptr) {
      // final layer: fused global pooling, no h write needed
      atomicMax(&poolkey[b * DD + t], keyenc(fmaxf(nh0, nh1)));
      return;
    }
    hrow[0][t] = nh0; hrow[1][t] = nh1;
    h[(size_t)(b * NN + i0) * DD + t] = nh0;
    h[(size_t)(b * NN + i0 + 1) * DD + t] = nh1;
    float m0 = nh0, m1 = nh1;
#pragma unroll
    for (int mask = 32; mask >= 1; mask >>= 1) {
      m0 = fmaxf(m0, __shfl_xor(m0, mask));
      m1 = fmaxf(m1, __shfl_xor(m1, mask));
    }
    if (lane0) { redB[wv][0] = m0; redB[wv][1] = m1; }
  }
  __syncthreads();
  // ---- next-layer qkv from LDS hrow (3 outputs x 2 rows per thread) ----
  {
    float mx0 = fmaxf(redB[0][0], redB[1][0]);
    float mx1 = fmaxf(redB[0][1], redB[1][1]);
    const float4* Q4 = reinterpret_cast<const float4*>(qWn + (size_t)t * DD);
    const float4* K4 = reinterpret_cast<const float4*>(kWn + (size_t)t * DD);
    const float4* V4 = reinterpret_cast<const float4*>(vWn + (size_t)t * DD);
    float aq0 = NEGINF, aq1 = NEGINF, ak0 = NEGINF, ak1 = NEGINF,
          av0 = NEGINF, av1 = NEGINF;
#pragma unroll 4
    for (int j4 = 0; j4 < DD / 4; j4++) {
      float4 x0 = *reinterpret_cast<const float4*>(&hrow[0][j4 * 4]);
      float4 x1 = *reinterpret_cast<const float4*>(&hrow[1][j4 * 4]);
      float4 wq = Q4[j4], wk = K4[j4], wvv = V4[j4];
      aq0 = fmaxf(aq0, x0.x + wq.x); aq0 = fmaxf(aq0, x0.y + wq.y);
      aq0 = fmaxf(aq0, x0.z + wq.z); aq0 = fmaxf(aq0, x0.w + wq.w);
      aq1 = fmaxf(aq1, x1.x + wq.x); aq1 = fmaxf(aq1, x1.y + wq.y);
      aq1 = fmaxf(aq1, x1.z + wq.z); aq1 = fmaxf(aq1, x1.w + wq.w);
      ak0 = fmaxf(ak0, x0.x + wk.x); ak0 = fmaxf(ak0, x0.y + wk.y);
      ak0 = fmaxf(ak0, x0.z + wk.z); ak0 = fmaxf(ak0, x0.w + wk.w);
      ak1 = fmaxf(ak1, x1.x + wk.x); ak1 = fmaxf(ak1, x1.y + wk.y);
      ak1 = fmaxf(ak1, x1.z + wk.z); ak1 = fmaxf(ak1, x1.w + wk.w);
      av0 = fmaxf(av0, x0.x + wvv.x); av0 = fmaxf(av0, x0.y + wvv.y);
      av0 = fmaxf(av0, x0.z + wvv.z); av0 = fmaxf(av0, x0.w + wvv.w);
      av1 = fmaxf(av1, x1.x + wvv.x); av1 = fmaxf(av1, x1.y + wvv.y);
      av1 = fmaxf(av1, x1.z + wvv.z); av1 = fmaxf(av1, x1.w + wvv.w);
    }
    size_t o0 = (size_t)(b * NN + i0) * DD + t, o1 = o0 + DD;
    qo[o0] = aq0 - mx0; qo[o1] = aq1 - mx1;
    ko[o0] = ak0 - mx0; ko[o1] = ak1 - mx1;
    vo[o0] = av0 - mx0; vo[o1] = av1 - mx1;
  }
}

// ============ K4: head from pooled keys. grid (8, B), 128 threads =========
__global__ __launch_bounds__(128) void head_kernel(
    const unsigned* __restrict__ poolkey, const float* __restrict__ hW,
    const float* __restrict__ lscale, float* __restrict__ out) {
  int cb = blockIdx.x, b = blockIdx.y;
  __shared__ float pooled[DD];
  int t = threadIdx.x;
  pooled[t] = keydec(poolkey[b * DD + t]);
  __syncthreads();
  if (t < 125) {
    int c = cb * 125 + t;
    const float4* W4 = reinterpret_cast<const float4*>(hW + (size_t)c * DD);
    float acc = NEGINF;
#pragma unroll 4
    for (int k4 = 0; k4 < DD / 4; k4++) {
      float4 w = W4[k4];
      float4 p = *reinterpret_cast<const float4*>(&pooled[k4 * 4]);
      acc = fmaxf(acc, p.x + w.x); acc = fmaxf(acc, p.y + w.y);
      acc = fmaxf(acc, p.z + w.z); acc = fmaxf(acc, p.w + w.w);
    }
    out[(size_t)b * CC + c] = acc * lscale[0];
  }
}

extern "C" void kernel_launch(void* const* d_in, const int* in_sizes, int n_in,
                              void* d_out, int out_size, void* d_ws, size_t ws_size,
                              hipStream_t stream) {
  const float* x = (const float*)d_in[0];
  const float* embed_W = (const float*)d_in[1];
  const float* pos = (const float*)d_in[2];
  const float* qW[2] = {(const float*)d_in[3], (const float*)d_in[9]};
  const float* kW[2] = {(const float*)d_in[4], (const float*)d_in[10]};
  const float* vW[2] = {(const float*)d_in[5], (const float*)d_in[11]};
  const float* f1W[2] = {(const float*)d_in[6], (const float*)d_in[12]};
  const float* f2W[2] = {(const float*)d_in[7], (const float*)d_in[13]};
  const float* tau[2] = {(const float*)d_in[8], (const float*)d_in[14]};
  const float* headW = (const float*)d_in[15];
  const float* lscale = (const float*)d_in[16];
  float* out = (float*)d_out;

  float* ws = (float*)d_ws;
  size_t o = 0;
  float* h = ws + o; o += (size_t)BDIM * NN * DD;
  float* qb = ws + o; o += (size_t)BDIM * NN * DD;
  float* kb = ws + o; o += (size_t)BDIM * NN * DD;
  float* vb = ws + o; o += (size_t)BDIM * NN * DD;
  float* k2 = ws + o; o += (size_t)BDIM * NN * DD;
  float* v2 = ws + o; o += (size_t)BDIM * NN * DD;
  unsigned* poolkey = (unsigned*)(ws + o); o += (size_t)BDIM * DD;

  // K1: embed + qkv(L0); also inits poolkey
  embed_qkv_kernel<<<dim3(98, BDIM), 128, 0, stream>>>(
      x, embed_W, pos, qW[0], kW[0], vW[0], h, qb, kb, vb, poolkey);
  // K2: attn(L0)+ffn(L0)+qkv(L1); q overwritten in place, k/v double-buffered
  layer_kernel<<<dim3(98, BDIM), 128, 0, stream>>>(
      qb, kb, vb, h, f1W[0], f2W[0], tau[0], qW[1], kW[1], vW[1], qb, k2, v2,
      poolkey);
  // K3: attn(L1)+ffn(L1) + fused global pooling via atomicMax keys
  layer_kernel<<<dim3(98, BDIM), 128, 0, stream>>>(
      qb, k2, v2, h, f1W[1], f2W[1], tau[1], nullptr, nullptr, nullptr,
      nullptr, nullptr, nullptr, poolkey);
  // K4: head from pooled
  head_kernel<<<dim3(8, BDIM), 128, 0, stream>>>(poolkey, headW, lscale, out);
}